// Round 1
// baseline (147.745 us; speedup 1.0000x reference)
//
#include <hip/hip_runtime.h>
#include <hip/hip_bf16.h>
#include <math.h>

#define T_TRACKS 1024
#define HIDDEN 128
#define LATENT 16
#define NGRID 16
#define NCELLS 256
#define OUTD 128

// Kernel 1: vals[j][l] = hidden[j] @ W_enc[:,l] + b_enc[l]   -> ws (f32, 1024x16)
__global__ __launch_bounds__(256) void vals_kernel(const float* __restrict__ hidden,
                                                   const float* __restrict__ W_enc,
                                                   const float* __restrict__ b_enc,
                                                   float* __restrict__ vals) {
    int idx = blockIdx.x * 256 + threadIdx.x;   // 0..16383
    int j = idx >> 4;
    int l = idx & 15;
    const float* h = hidden + j * HIDDEN;
    float acc = b_enc[l];
#pragma unroll 8
    for (int k = 0; k < HIDDEN; k++) {
        acc += h[k] * W_enc[k * LATENT + l];
    }
    vals[idx] = acc;
}

// Kernel 2: per-track occupancy grid (last-write-wins via atomicMax on neighbor
// index) + fused 4096->128 GEMV + bias + relu.
__global__ __launch_bounds__(256) void pool_kernel(const float* __restrict__ obs2,
                                                   const float* __restrict__ vals,
                                                   const float* __restrict__ W_emb,
                                                   const float* __restrict__ b_emb,
                                                   float* __restrict__ out) {
    const int i = blockIdx.x;     // track
    const int tid = threadIdx.x;  // 0..255

    __shared__ int owner[NCELLS];
    __shared__ float occ[NCELLS * LATENT];   // 16 KiB
    __shared__ float partial[OUTD];

    owner[tid] = -1;

    // obs_i with NaN-row masking (any NaN coord -> (0,0))
    float oix = obs2[i * 2 + 0];
    float oiy = obs2[i * 2 + 1];
    if (isnan(oix) || isnan(oiy)) { oix = 0.0f; oiy = 0.0f; }

    __syncthreads();

    // Phase 1: each neighbor j maps to a cell; max-j wins (== numpy last write)
    for (int j = tid; j < T_TRACKS; j += 256) {
        if (j == i) continue;
        float ox = obs2[j * 2 + 0];
        float oy = obs2[j * 2 + 1];
        if (isnan(ox) || isnan(oy)) { ox = 0.0f; oy = 0.0f; }
        float gx = (ox - oix) * 0.5f + 8.0f;
        float gy = (oy - oiy) * 0.5f + 8.0f;
        bool inr = (gx >= 0.0f) && (gx < 16.0f) && (gy >= 0.0f) && (gy < 16.0f);
        // out-of-range neighbors scatter value 0 into cell 0 (reference semantics)
        int c = inr ? ((int)gx * NGRID + (int)gy) : 0;
        atomicMax(&owner[c], j);
    }
    __syncthreads();

    // Phase 2: gather winning neighbor's vals into the occupancy grid
    {
        int j = owner[tid];  // tid == cell index
        bool valid = false;
        if (j >= 0) {
            float ox = obs2[j * 2 + 0];
            float oy = obs2[j * 2 + 1];
            if (isnan(ox) || isnan(oy)) { ox = 0.0f; oy = 0.0f; }
            float gx = (ox - oix) * 0.5f + 8.0f;
            float gy = (oy - oiy) * 0.5f + 8.0f;
            valid = (gx >= 0.0f) && (gx < 16.0f) && (gy >= 0.0f) && (gy < 16.0f);
        }
        const float* vj = vals + (j >= 0 ? j : 0) * LATENT;
#pragma unroll
        for (int l = 0; l < LATENT; l++) {
            occ[tid * LATENT + l] = valid ? vj[l] : 0.0f;
        }
    }
    __syncthreads();

    // Phase 3: out[i][o] = relu( sum_{c,l} occ[c][l] * W_emb[(l*256+c)*128 + o] + b_emb[o] )
    // 256 threads: o = tid&127, each half covers 128 cells.
    const int o = tid & (OUTD - 1);
    const int half = tid >> 7;
    const int cbase = half * 128;
    float acc = 0.0f;
    for (int c = cbase; c < cbase + 128; c++) {
#pragma unroll
        for (int l = 0; l < LATENT; l++) {
            acc += occ[c * LATENT + l] * W_emb[(l * NCELLS + c) * OUTD + o];
        }
    }
    if (half == 0) partial[o] = acc;
    __syncthreads();
    if (half == 1) {
        out[i * OUTD + o] = fmaxf(acc + partial[o] + b_emb[o], 0.0f);
    }
}

extern "C" void kernel_launch(void* const* d_in, const int* in_sizes, int n_in,
                              void* d_out, int out_size, void* d_ws, size_t ws_size,
                              hipStream_t stream) {
    const float* hidden = (const float*)d_in[0];   // [1024,128]
    // d_in[1] = obs1 (unused by reference)
    const float* obs2   = (const float*)d_in[2];   // [1024,2]
    const float* W_enc  = (const float*)d_in[3];   // [128,16]
    const float* b_enc  = (const float*)d_in[4];   // [16]
    const float* W_emb  = (const float*)d_in[5];   // [4096,128]
    const float* b_emb  = (const float*)d_in[6];   // [128]
    float* out = (float*)d_out;                    // [1024,128]

    float* vals = (float*)d_ws;                    // [1024,16] f32 = 64 KiB

    vals_kernel<<<(T_TRACKS * LATENT) / 256, 256, 0, stream>>>(hidden, W_enc, b_enc, vals);
    pool_kernel<<<T_TRACKS, 256, 0, stream>>>(obs2, vals, W_emb, b_emb, out);
}

// Round 3
// 93.564 us; speedup vs baseline: 1.5791x; 1.5791x over previous
//
#include <hip/hip_runtime.h>
#include <hip/hip_bf16.h>
#include <math.h>

#define T_TRACKS 1024
#define HIDDEN 128
#define LATENT 16
#define NGRID 16
#define NCELLS 256
#define KDIM 4096
#define OUTD 128

typedef unsigned short ushort_t;
typedef __attribute__((ext_vector_type(8))) short frag_ab;   // 8 bf16
typedef __attribute__((ext_vector_type(4))) float f32x4;

static __device__ inline ushort_t f2bf(float x) {
    __hip_bfloat16 h = __float2bfloat16(x);
    return *reinterpret_cast<ushort_t*>(&h);
}

// ---------------- ws layout (byte offsets) ----------------
// vals_bf16 [1024][16]           @ 0         (32 KB)
// W_t bf16 [128 o][4096 k]       @ 32768     (1 MB)
// occ bf16 [1024][4096]          @ 1081344   (8 MB)
// accum f32 [1024][128]          @ 9469952   (512 KB)
#define WS_VALS 0
#define WS_WT   32768
#define WS_OCC  1081344
#define WS_ACC  9469952
#define WS_NEED 9994240

// ============ K1: prep (vals bf16 | W_emb transpose->bf16 | zero accum) ============
__global__ __launch_bounds__(256) void prep_kernel(const float* __restrict__ hidden,
                                                   const float* __restrict__ W_enc,
                                                   const float* __restrict__ b_enc,
                                                   const float* __restrict__ W_emb,
                                                   ushort_t* __restrict__ vals_bf16,
                                                   ushort_t* __restrict__ W_t,
                                                   float* __restrict__ accum) {
    const int b = blockIdx.x;
    const int tid = threadIdx.x;
    if (b < 64) {
        // vals[j][l] = hidden[j] @ W_enc[:,l] + b_enc[l]  -> bf16
        int idx = b * 256 + tid;           // 0..16383
        int j = idx >> 4, l = idx & 15;
        const float* h = hidden + j * HIDDEN;
        float acc = b_enc[l];
#pragma unroll 8
        for (int k = 0; k < HIDDEN; k++) acc += h[k] * W_enc[k * LATENT + l];
        vals_bf16[idx] = f2bf(acc);
    } else if (b < 320) {
        // W_t[o][k] = bf16(W_emb[k][o]); thread handles (o, 8 consecutive k)
        int idx = (b - 64) * 256 + tid;    // 0..65535
        int kc = idx >> 7;                 // 0..511 (chunk of 8 k)
        int o = idx & 127;
        ushort_t tmp[8];
#pragma unroll
        for (int u = 0; u < 8; u++) tmp[u] = f2bf(W_emb[(kc * 8 + u) * OUTD + o]);
        *reinterpret_cast<uint4*>(W_t + o * KDIM + kc * 8) = *reinterpret_cast<uint4*>(tmp);
    } else {
        // zero accum: 32768 float4
        int idx = (b - 320) * 256 + tid;   // 0..32767
        float4 z; z.x = z.y = z.z = z.w = 0.0f;
        reinterpret_cast<float4*>(accum)[idx] = z;
    }
}

// ============ K2: build occ rows (bf16, k = l*256 + c order) ============
__global__ __launch_bounds__(256) void occ_kernel(const float* __restrict__ obs2,
                                                  const ushort_t* __restrict__ vals_bf16,
                                                  ushort_t* __restrict__ occ) {
    const int i = blockIdx.x;
    const int tid = threadIdx.x;
    __shared__ int owner[NCELLS];
    owner[tid] = -1;

    float oix = obs2[i * 2 + 0];
    float oiy = obs2[i * 2 + 1];
    if (isnan(oix) || isnan(oiy)) { oix = 0.0f; oiy = 0.0f; }
    __syncthreads();

    for (int j = tid; j < T_TRACKS; j += 256) {
        if (j == i) continue;
        float ox = obs2[j * 2 + 0];
        float oy = obs2[j * 2 + 1];
        if (isnan(ox) || isnan(oy)) { ox = 0.0f; oy = 0.0f; }
        float gx = (ox - oix) * 0.5f + 8.0f;
        float gy = (oy - oiy) * 0.5f + 8.0f;
        bool inr = (gx >= 0.0f) && (gx < 16.0f) && (gy >= 0.0f) && (gy < 16.0f);
        int c = inr ? ((int)gx * NGRID + (int)gy) : 0;   // OOR scatters 0 into cell 0
        atomicMax(&owner[c], j);
    }
    __syncthreads();

    // thread t: latent l = t>>4, cells cbase..cbase+15; writes 32B contiguous
    const int l = tid >> 4;
    const int cbase = (tid & 15) * 16;
    ushort_t outv[16];
#pragma unroll
    for (int u = 0; u < 16; u++) {
        int c = cbase + u;
        int j = owner[c];
        bool valid = (j >= 0);
        if (c == 0 && valid) {
            // cell 0's winner may be an out-of-range neighbor (value 0)
            float ox = obs2[j * 2 + 0];
            float oy = obs2[j * 2 + 1];
            if (isnan(ox) || isnan(oy)) { ox = 0.0f; oy = 0.0f; }
            float gx = (ox - oix) * 0.5f + 8.0f;
            float gy = (oy - oiy) * 0.5f + 8.0f;
            valid = (gx >= 0.0f) && (gx < 16.0f) && (gy >= 0.0f) && (gy < 16.0f);
        }
        int jj = (j >= 0) ? j : 0;   // clamp: never index below the buffer
        outv[u] = valid ? vals_bf16[jj * LATENT + l] : (ushort_t)0;
    }
    uint4* dst = reinterpret_cast<uint4*>(occ + i * KDIM + tid * 16);
    dst[0] = reinterpret_cast<uint4*>(outv)[0];
    dst[1] = reinterpret_cast<uint4*>(outv)[1];
}

// ============ K3: MFMA GEMM, K-split partials via atomicAdd ============
// grid = 256: kt = blockIdx & 15 (Kseg=256), mt = blockIdx >> 4 (Mtile=64)
#define BK 128
#define LDSTR 136   // row stride in bf16 elems (128 + 8 pad -> 272 B, bank-friendly)
__global__ __launch_bounds__(256) void gemm_kernel(const ushort_t* __restrict__ occ,
                                                   const ushort_t* __restrict__ W_t,
                                                   float* __restrict__ accum) {
    const int tid = threadIdx.x;
    const int kt = blockIdx.x & 15;
    const int mt = blockIdx.x >> 4;
    const int wave = tid >> 6;
    const int lane = tid & 63;
    const int lrow = lane & 15;
    const int quad = lane >> 4;

    __shared__ ushort_t As[64 * LDSTR];    // 17408 B
    __shared__ ushort_t Bs[128 * LDSTR];   // 34816 B

    f32x4 acc[8];
#pragma unroll
    for (int nt = 0; nt < 8; nt++) acc[nt] = (f32x4){0.f, 0.f, 0.f, 0.f};

    for (int chunk = 0; chunk < 2; chunk++) {
        const int k0 = kt * 256 + chunk * BK;
        // stage A: 64 rows x 128 k = 64*16 = 1024 16B-granules
        for (int g = tid; g < 1024; g += 256) {
            int r = g >> 4, cs = g & 15;
            uint4 v = *reinterpret_cast<const uint4*>(occ + (mt * 64 + r) * KDIM + k0 + cs * 8);
            *reinterpret_cast<uint4*>(As + r * LDSTR + cs * 8) = v;
        }
        // stage B: 128 rows x 128 k = 128*16 = 2048 granules
        for (int g = tid; g < 2048; g += 256) {
            int n = g >> 4, cs = g & 15;
            uint4 v = *reinterpret_cast<const uint4*>(W_t + n * KDIM + k0 + cs * 8);
            *reinterpret_cast<uint4*>(Bs + n * LDSTR + cs * 8) = v;
        }
        __syncthreads();
#pragma unroll
        for (int ks = 0; ks < 4; ks++) {   // K=32 per mfma
            const int koff = ks * 32 + quad * 8;
            frag_ab a = *reinterpret_cast<const frag_ab*>(&As[(wave * 16 + lrow) * LDSTR + koff]);
#pragma unroll
            for (int nt = 0; nt < 8; nt++) {
                frag_ab bfr = *reinterpret_cast<const frag_ab*>(&Bs[(nt * 16 + lrow) * LDSTR + koff]);
                acc[nt] = __builtin_amdgcn_mfma_f32_16x16x32_bf16(a, bfr, acc[nt], 0, 0, 0);
            }
        }
        __syncthreads();
    }
    // epilogue: C/D layout col=lane&15, row=quad*4+reg  (m89/m91-verified)
#pragma unroll
    for (int nt = 0; nt < 8; nt++) {
        int n = nt * 16 + lrow;
#pragma unroll
        for (int reg = 0; reg < 4; reg++) {
            int m = mt * 64 + wave * 16 + quad * 4 + reg;
            atomicAdd(&accum[m * OUTD + n], acc[nt][reg]);
        }
    }
}

// ============ K4: bias + relu ============
__global__ __launch_bounds__(256) void epilogue_kernel(const float* __restrict__ accum,
                                                       const float* __restrict__ b_emb,
                                                       float* __restrict__ out) {
    int idx = blockIdx.x * 256 + threadIdx.x;   // 0..32767 float4s
    float4 v = reinterpret_cast<const float4*>(accum)[idx];
    float4 bv = reinterpret_cast<const float4*>(b_emb)[idx & 31];
    float4 r;
    r.x = fmaxf(v.x + bv.x, 0.0f);
    r.y = fmaxf(v.y + bv.y, 0.0f);
    r.z = fmaxf(v.z + bv.z, 0.0f);
    r.w = fmaxf(v.w + bv.w, 0.0f);
    reinterpret_cast<float4*>(out)[idx] = r;
}

// ================= Round-1 fallback (f32, fused) for small ws =================
__global__ __launch_bounds__(256) void vals_kernel_f32(const float* __restrict__ hidden,
                                                       const float* __restrict__ W_enc,
                                                       const float* __restrict__ b_enc,
                                                       float* __restrict__ vals) {
    int idx = blockIdx.x * 256 + threadIdx.x;
    int j = idx >> 4, l = idx & 15;
    const float* h = hidden + j * HIDDEN;
    float acc = b_enc[l];
#pragma unroll 8
    for (int k = 0; k < HIDDEN; k++) acc += h[k] * W_enc[k * LATENT + l];
    vals[idx] = acc;
}

__global__ __launch_bounds__(256) void pool_kernel_f32(const float* __restrict__ obs2,
                                                       const float* __restrict__ vals,
                                                       const float* __restrict__ W_emb,
                                                       const float* __restrict__ b_emb,
                                                       float* __restrict__ out) {
    const int i = blockIdx.x;
    const int tid = threadIdx.x;
    __shared__ int owner[NCELLS];
    __shared__ float occ[NCELLS * LATENT];
    __shared__ float partial[OUTD];
    owner[tid] = -1;
    float oix = obs2[i * 2 + 0];
    float oiy = obs2[i * 2 + 1];
    if (isnan(oix) || isnan(oiy)) { oix = 0.0f; oiy = 0.0f; }
    __syncthreads();
    for (int j = tid; j < T_TRACKS; j += 256) {
        if (j == i) continue;
        float ox = obs2[j * 2 + 0], oy = obs2[j * 2 + 1];
        if (isnan(ox) || isnan(oy)) { ox = 0.0f; oy = 0.0f; }
        float gx = (ox - oix) * 0.5f + 8.0f;
        float gy = (oy - oiy) * 0.5f + 8.0f;
        bool inr = (gx >= 0.0f) && (gx < 16.0f) && (gy >= 0.0f) && (gy < 16.0f);
        int c = inr ? ((int)gx * NGRID + (int)gy) : 0;
        atomicMax(&owner[c], j);
    }
    __syncthreads();
    {
        int j = owner[tid];
        bool valid = false;
        if (j >= 0) {
            float ox = obs2[j * 2 + 0], oy = obs2[j * 2 + 1];
            if (isnan(ox) || isnan(oy)) { ox = 0.0f; oy = 0.0f; }
            float gx = (ox - oix) * 0.5f + 8.0f;
            float gy = (oy - oiy) * 0.5f + 8.0f;
            valid = (gx >= 0.0f) && (gx < 16.0f) && (gy >= 0.0f) && (gy < 16.0f);
        }
        const float* vj = vals + (j >= 0 ? j : 0) * LATENT;
#pragma unroll
        for (int l = 0; l < LATENT; l++) occ[tid * LATENT + l] = valid ? vj[l] : 0.0f;
    }
    __syncthreads();
    const int o = tid & (OUTD - 1);
    const int half = tid >> 7;
    const int cbase = half * 128;
    float acc = 0.0f;
    for (int c = cbase; c < cbase + 128; c++) {
#pragma unroll
        for (int l = 0; l < LATENT; l++)
            acc += occ[c * LATENT + l] * W_emb[(l * NCELLS + c) * OUTD + o];
    }
    if (half == 0) partial[o] = acc;
    __syncthreads();
    if (half == 1) out[i * OUTD + o] = fmaxf(acc + partial[o] + b_emb[o], 0.0f);
}

extern "C" void kernel_launch(void* const* d_in, const int* in_sizes, int n_in,
                              void* d_out, int out_size, void* d_ws, size_t ws_size,
                              hipStream_t stream) {
    const float* hidden = (const float*)d_in[0];   // [1024,128]
    const float* obs2   = (const float*)d_in[2];   // [1024,2]
    const float* W_enc  = (const float*)d_in[3];   // [128,16]
    const float* b_enc  = (const float*)d_in[4];   // [16]
    const float* W_emb  = (const float*)d_in[5];   // [4096,128]
    const float* b_emb  = (const float*)d_in[6];   // [128]
    float* out = (float*)d_out;                    // [1024,128]

    if (ws_size < (size_t)WS_NEED) {
        // fallback: round-1 verified f32 path
        float* vals = (float*)d_ws;
        vals_kernel_f32<<<(T_TRACKS * LATENT) / 256, 256, 0, stream>>>(hidden, W_enc, b_enc, vals);
        pool_kernel_f32<<<T_TRACKS, 256, 0, stream>>>(obs2, vals, W_emb, b_emb, out);
        return;
    }

    char* ws = (char*)d_ws;
    ushort_t* vals_bf16 = (ushort_t*)(ws + WS_VALS);
    ushort_t* W_t       = (ushort_t*)(ws + WS_WT);
    ushort_t* occ       = (ushort_t*)(ws + WS_OCC);
    float*    accum     = (float*)(ws + WS_ACC);

    prep_kernel<<<448, 256, 0, stream>>>(hidden, W_enc, b_enc, W_emb, vals_bf16, W_t, accum);
    occ_kernel<<<T_TRACKS, 256, 0, stream>>>(obs2, vals_bf16, occ);
    gemm_kernel<<<256, 256, 0, stream>>>(occ, W_t, accum);
    epilogue_kernel<<<128, 256, 0, stream>>>(accum, b_emb, out);
}

// Round 4
// 89.981 us; speedup vs baseline: 1.6420x; 1.0398x over previous
//
#include <hip/hip_runtime.h>
#include <hip/hip_bf16.h>
#include <math.h>

#define T_TRACKS 1024
#define HIDDEN 128
#define LATENT 16
#define NGRID 16
#define NCELLS 256
#define KDIM 4096
#define OUTD 128

typedef unsigned short ushort_t;
typedef __attribute__((ext_vector_type(8))) short frag_ab;   // 8 bf16
typedef __attribute__((ext_vector_type(4))) float f32x4;

static __device__ inline ushort_t f2bf(float x) {
    __hip_bfloat16 h = __float2bfloat16(x);
    return *reinterpret_cast<ushort_t*>(&h);
}

// ---------------- ws layout (byte offsets) ----------------
// vals_bf16 [1024][16]             @ 0         (32 KB)
// W_t bf16 [128 o][4096 k]         @ 32768     (1 MB)
// occ bf16 [1024][4096]            @ 1081344   (8 MB)
// partial f32 [16 kt][1024][128]   @ 9469952   (8 MB)
#define WS_VALS 0
#define WS_WT   32768
#define WS_OCC  1081344
#define WS_PART 9469952
#define WS_NEED (9469952 + 8388608)

// ============ K1: prep (vals bf16 | W_emb transpose->bf16) ============
__global__ __launch_bounds__(256) void prep_kernel(const float* __restrict__ hidden,
                                                   const float* __restrict__ W_enc,
                                                   const float* __restrict__ b_enc,
                                                   const float* __restrict__ W_emb,
                                                   ushort_t* __restrict__ vals_bf16,
                                                   ushort_t* __restrict__ W_t) {
    const int b = blockIdx.x;
    const int tid = threadIdx.x;
    if (b < 64) {
        // vals[j][l] = hidden[j] @ W_enc[:,l] + b_enc[l]  -> bf16
        int idx = b * 256 + tid;           // 0..16383
        int j = idx >> 4, l = idx & 15;
        const float* h = hidden + j * HIDDEN;
        float acc = b_enc[l];
#pragma unroll 8
        for (int k = 0; k < HIDDEN; k++) acc += h[k] * W_enc[k * LATENT + l];
        vals_bf16[idx] = f2bf(acc);
    } else {
        // W_t[o][k] = bf16(W_emb[k][o]); thread handles (o, 8 consecutive k)
        int idx = (b - 64) * 256 + tid;    // 0..65535
        int kc = idx >> 7;                 // 0..511 (chunk of 8 k)
        int o = idx & 127;
        ushort_t tmp[8];
#pragma unroll
        for (int u = 0; u < 8; u++) tmp[u] = f2bf(W_emb[(kc * 8 + u) * OUTD + o]);
        *reinterpret_cast<uint4*>(W_t + o * KDIM + kc * 8) = *reinterpret_cast<uint4*>(tmp);
    }
}

// ============ K2: build occ rows (bf16, k = l*256 + c order) ============
// Thread t == cell c: winner's 16 latents read as one contiguous 32B load,
// transposed through LDS, then 8KB row stored coalesced.
__global__ __launch_bounds__(256) void occ_kernel(const float* __restrict__ obs2,
                                                  const ushort_t* __restrict__ vals_bf16,
                                                  ushort_t* __restrict__ occ) {
    const int i = blockIdx.x;
    const int tid = threadIdx.x;
    __shared__ int owner[NCELLS];
    __shared__ ushort_t socc[LATENT * NCELLS];   // [l][c], 8 KB
    owner[tid] = -1;

    float oix = obs2[i * 2 + 0];
    float oiy = obs2[i * 2 + 1];
    if (isnan(oix) || isnan(oiy)) { oix = 0.0f; oiy = 0.0f; }
    __syncthreads();

    for (int j = tid; j < T_TRACKS; j += 256) {
        if (j == i) continue;
        float ox = obs2[j * 2 + 0];
        float oy = obs2[j * 2 + 1];
        if (isnan(ox) || isnan(oy)) { ox = 0.0f; oy = 0.0f; }
        float gx = (ox - oix) * 0.5f + 8.0f;
        float gy = (oy - oiy) * 0.5f + 8.0f;
        bool inr = (gx >= 0.0f) && (gx < 16.0f) && (gy >= 0.0f) && (gy < 16.0f);
        int c = inr ? ((int)gx * NGRID + (int)gy) : 0;   // OOR scatters 0 into cell 0
        atomicMax(&owner[c], j);
    }
    __syncthreads();

    {
        const int c = tid;
        int j = owner[c];
        bool valid = (j >= 0);
        if (c == 0 && valid) {
            // cell 0's winner may be an out-of-range neighbor (value 0)
            float ox = obs2[j * 2 + 0];
            float oy = obs2[j * 2 + 1];
            if (isnan(ox) || isnan(oy)) { ox = 0.0f; oy = 0.0f; }
            float gx = (ox - oix) * 0.5f + 8.0f;
            float gy = (oy - oiy) * 0.5f + 8.0f;
            valid = (gx >= 0.0f) && (gx < 16.0f) && (gy >= 0.0f) && (gy < 16.0f);
        }
        int jj = (j >= 0) ? j : 0;
        ushort_t vv[16];
        *reinterpret_cast<uint4*>(vv)     = *reinterpret_cast<const uint4*>(vals_bf16 + jj * LATENT);
        *reinterpret_cast<uint4*>(vv + 8) = *reinterpret_cast<const uint4*>(vals_bf16 + jj * LATENT + 8);
#pragma unroll
        for (int l = 0; l < LATENT; l++) {
            socc[l * NCELLS + c] = valid ? vv[l] : (ushort_t)0;
        }
    }
    __syncthreads();

    // coalesced store of the 4096-elem row (512 uint4, 2 per thread)
    uint4* dst = reinterpret_cast<uint4*>(occ + i * KDIM);
    const uint4* src = reinterpret_cast<const uint4*>(socc);
    dst[tid]       = src[tid];
    dst[tid + 256] = src[tid + 256];
}

// ============ K3: MFMA GEMM, K-split partials (no atomics) ============
// grid = 256: kt = blockIdx & 15 (Kseg=256), mt = blockIdx >> 4 (Mtile=64)
#define BK 128
#define LDSTR 136   // row stride in bf16 elems (128 + 8 pad)
__global__ __launch_bounds__(256) void gemm_kernel(const ushort_t* __restrict__ occ,
                                                   const ushort_t* __restrict__ W_t,
                                                   float* __restrict__ partial) {
    const int tid = threadIdx.x;
    const int kt = blockIdx.x & 15;
    const int mt = blockIdx.x >> 4;
    const int wave = tid >> 6;
    const int lane = tid & 63;
    const int lrow = lane & 15;
    const int quad = lane >> 4;

    __shared__ ushort_t As[64 * LDSTR];    // 17408 B
    __shared__ ushort_t Bs[128 * LDSTR];   // 34816 B

    f32x4 acc[8];
#pragma unroll
    for (int nt = 0; nt < 8; nt++) acc[nt] = (f32x4){0.f, 0.f, 0.f, 0.f};

    for (int chunk = 0; chunk < 2; chunk++) {
        const int k0 = kt * 256 + chunk * BK;
        // stage A: 64 rows x 128 k = 1024 16B-granules
        for (int g = tid; g < 1024; g += 256) {
            int r = g >> 4, cs = g & 15;
            uint4 v = *reinterpret_cast<const uint4*>(occ + (mt * 64 + r) * KDIM + k0 + cs * 8);
            *reinterpret_cast<uint4*>(As + r * LDSTR + cs * 8) = v;
        }
        // stage B: 128 rows x 128 k = 2048 granules
        for (int g = tid; g < 2048; g += 256) {
            int n = g >> 4, cs = g & 15;
            uint4 v = *reinterpret_cast<const uint4*>(W_t + n * KDIM + k0 + cs * 8);
            *reinterpret_cast<uint4*>(Bs + n * LDSTR + cs * 8) = v;
        }
        __syncthreads();
#pragma unroll
        for (int ks = 0; ks < 4; ks++) {   // K=32 per mfma
            const int koff = ks * 32 + quad * 8;
            frag_ab a = *reinterpret_cast<const frag_ab*>(&As[(wave * 16 + lrow) * LDSTR + koff]);
#pragma unroll
            for (int nt = 0; nt < 8; nt++) {
                frag_ab bfr = *reinterpret_cast<const frag_ab*>(&Bs[(nt * 16 + lrow) * LDSTR + koff]);
                acc[nt] = __builtin_amdgcn_mfma_f32_16x16x32_bf16(a, bfr, acc[nt], 0, 0, 0);
            }
        }
        __syncthreads();
    }
    // C/D layout: col = lane&15, row = quad*4+reg (m89/m91-verified).
    // Plain stores into this block's private partial tile.
    float* pt = partial + (size_t)kt * (T_TRACKS * OUTD) + (mt * 64) * OUTD;
#pragma unroll
    for (int nt = 0; nt < 8; nt++) {
        int n = nt * 16 + lrow;
#pragma unroll
        for (int reg = 0; reg < 4; reg++) {
            int m = wave * 16 + quad * 4 + reg;
            pt[m * OUTD + n] = acc[nt][reg];
        }
    }
}

// ============ K4: reduce 16 partials + bias + relu ============
__global__ __launch_bounds__(256) void reduce_kernel(const float* __restrict__ partial,
                                                     const float* __restrict__ b_emb,
                                                     float* __restrict__ out) {
    int idx = blockIdx.x * 256 + threadIdx.x;   // 0..32767 (float4 groups of [1024][128])
    const float4* p4 = reinterpret_cast<const float4*>(partial);
    float4 s = p4[idx];
#pragma unroll
    for (int kt = 1; kt < 16; kt++) {
        float4 v = p4[kt * 32768 + idx];
        s.x += v.x; s.y += v.y; s.z += v.z; s.w += v.w;
    }
    float4 bv = reinterpret_cast<const float4*>(b_emb)[idx & 31];
    float4 r;
    r.x = fmaxf(s.x + bv.x, 0.0f);
    r.y = fmaxf(s.y + bv.y, 0.0f);
    r.z = fmaxf(s.z + bv.z, 0.0f);
    r.w = fmaxf(s.w + bv.w, 0.0f);
    reinterpret_cast<float4*>(out)[idx] = r;
}

// ================= Round-1 fallback (f32, fused) for small ws =================
__global__ __launch_bounds__(256) void vals_kernel_f32(const float* __restrict__ hidden,
                                                       const float* __restrict__ W_enc,
                                                       const float* __restrict__ b_enc,
                                                       float* __restrict__ vals) {
    int idx = blockIdx.x * 256 + threadIdx.x;
    int j = idx >> 4, l = idx & 15;
    const float* h = hidden + j * HIDDEN;
    float acc = b_enc[l];
#pragma unroll 8
    for (int k = 0; k < HIDDEN; k++) acc += h[k] * W_enc[k * LATENT + l];
    vals[idx] = acc;
}

__global__ __launch_bounds__(256) void pool_kernel_f32(const float* __restrict__ obs2,
                                                       const float* __restrict__ vals,
                                                       const float* __restrict__ W_emb,
                                                       const float* __restrict__ b_emb,
                                                       float* __restrict__ out) {
    const int i = blockIdx.x;
    const int tid = threadIdx.x;
    __shared__ int owner[NCELLS];
    __shared__ float occ[NCELLS * LATENT];
    __shared__ float partial[OUTD];
    owner[tid] = -1;
    float oix = obs2[i * 2 + 0];
    float oiy = obs2[i * 2 + 1];
    if (isnan(oix) || isnan(oiy)) { oix = 0.0f; oiy = 0.0f; }
    __syncthreads();
    for (int j = tid; j < T_TRACKS; j += 256) {
        if (j == i) continue;
        float ox = obs2[j * 2 + 0], oy = obs2[j * 2 + 1];
        if (isnan(ox) || isnan(oy)) { ox = 0.0f; oy = 0.0f; }
        float gx = (ox - oix) * 0.5f + 8.0f;
        float gy = (oy - oiy) * 0.5f + 8.0f;
        bool inr = (gx >= 0.0f) && (gx < 16.0f) && (gy >= 0.0f) && (gy < 16.0f);
        int c = inr ? ((int)gx * NGRID + (int)gy) : 0;
        atomicMax(&owner[c], j);
    }
    __syncthreads();
    {
        int j = owner[tid];
        bool valid = false;
        if (j >= 0) {
            float ox = obs2[j * 2 + 0], oy = obs2[j * 2 + 1];
            if (isnan(ox) || isnan(oy)) { ox = 0.0f; oy = 0.0f; }
            float gx = (ox - oix) * 0.5f + 8.0f;
            float gy = (oy - oiy) * 0.5f + 8.0f;
            valid = (gx >= 0.0f) && (gx < 16.0f) && (gy >= 0.0f) && (gy < 16.0f);
        }
        const float* vj = vals + (j >= 0 ? j : 0) * LATENT;
#pragma unroll
        for (int l = 0; l < LATENT; l++) occ[tid * LATENT + l] = valid ? vj[l] : 0.0f;
    }
    __syncthreads();
    const int o = tid & (OUTD - 1);
    const int half = tid >> 7;
    const int cbase = half * 128;
    float acc = 0.0f;
    for (int c = cbase; c < cbase + 128; c++) {
#pragma unroll
        for (int l = 0; l < LATENT; l++)
            acc += occ[c * LATENT + l] * W_emb[(l * NCELLS + c) * OUTD + o];
    }
    if (half == 0) partial[o] = acc;
    __syncthreads();
    if (half == 1) out[i * OUTD + o] = fmaxf(acc + partial[o] + b_emb[o], 0.0f);
}

extern "C" void kernel_launch(void* const* d_in, const int* in_sizes, int n_in,
                              void* d_out, int out_size, void* d_ws, size_t ws_size,
                              hipStream_t stream) {
    const float* hidden = (const float*)d_in[0];   // [1024,128]
    const float* obs2   = (const float*)d_in[2];   // [1024,2]
    const float* W_enc  = (const float*)d_in[3];   // [128,16]
    const float* b_enc  = (const float*)d_in[4];   // [16]
    const float* W_emb  = (const float*)d_in[5];   // [4096,128]
    const float* b_emb  = (const float*)d_in[6];   // [128]
    float* out = (float*)d_out;                    // [1024,128]

    if (ws_size < (size_t)WS_NEED) {
        // fallback: round-1 verified f32 path
        float* vals = (float*)d_ws;
        vals_kernel_f32<<<(T_TRACKS * LATENT) / 256, 256, 0, stream>>>(hidden, W_enc, b_enc, vals);
        pool_kernel_f32<<<T_TRACKS, 256, 0, stream>>>(obs2, vals, W_emb, b_emb, out);
        return;
    }

    char* ws = (char*)d_ws;
    ushort_t* vals_bf16 = (ushort_t*)(ws + WS_VALS);
    ushort_t* W_t       = (ushort_t*)(ws + WS_WT);
    ushort_t* occ       = (ushort_t*)(ws + WS_OCC);
    float*    partial   = (float*)(ws + WS_PART);

    prep_kernel<<<320, 256, 0, stream>>>(hidden, W_enc, b_enc, W_emb, vals_bf16, W_t);
    occ_kernel<<<T_TRACKS, 256, 0, stream>>>(obs2, vals_bf16, occ);
    gemm_kernel<<<256, 256, 0, stream>>>(occ, W_t, partial);
    reduce_kernel<<<128, 256, 0, stream>>>(partial, b_emb, out);
}